// Round 13
// baseline (89.945 us; speedup 1.0000x reference)
//
#include <hip/hip_runtime.h>

#define NBATCH 8192
#define NELEC  16
#define NMO    32
#define NCONF  64
#define NS     8          // NUP == NDOWN == 8
#define TSTR   20         // A (fp32) row stride in floats (80 B: 16B-aligned for b128)
#define TSZ    (NMO * TSTR)
#define TSTRH  24         // D (fp16) row stride in HALVES (48 B: 16B-aligned for b128)
#define TSZH   (NMO * TSTRH)

typedef float    v2f   __attribute__((ext_vector_type(2)));
typedef _Float16 half8 __attribute__((ext_vector_type(8)));

__device__ __forceinline__ v2f pkfma(v2f a, v2f b, v2f c) {
#if __has_builtin(__builtin_elementwise_fma)
    return __builtin_elementwise_fma(a, b, c);
#else
    return a * b + c;
#endif
}
__device__ __forceinline__ v2f bc2(float s) { return (v2f){s, s}; }
__device__ __forceinline__ float getel2(const v2f (&R)[4], int j) {
    return (j & 1) ? R[j >> 1].y : R[j >> 1].x;
}
__device__ __forceinline__ void setel2(v2f (&R)[4], int j, float v) {
    if (j & 1) R[j >> 1].y = v; else R[j >> 1].x = v;
}

// PROVEN solve (byte-identical to R12, absmax 20288): fp32 A from LDS,
// fp16 D from LDS (D enters linearly -> no kappa amplification; R11 proved
// fp16-A fails at 4e8). In-place no-pivot LU packed over column pairs;
// tr = sum_k <col_k(A'^-1), row_k(D')>, unit-RHS solves packed over k pairs.
// R3/R4 lesson: rows of D' pair with columns of A'^-1 — keep this pairing.
__device__ __forceinline__ void solve8T(const float* __restrict__ MOT,
                                        const _Float16* __restrict__ D2T,
                                        const int (&cols)[NS], int eoff,
                                        float& det_out, float& tr_out)
{
    v2f A2[NS][4];                    // row j, pair p = cols {2p, 2p+1}
    #pragma unroll
    for (int j = 0; j < NS; ++j) {
        const float4* pa = (const float4*)(MOT + cols[j] * TSTR + eoff);
        float4 a0 = pa[0], a1 = pa[1];
        A2[j][0] = (v2f){a0.x, a0.y};
        A2[j][1] = (v2f){a0.z, a0.w};
        A2[j][2] = (v2f){a1.x, a1.y};
        A2[j][3] = (v2f){a1.z, a1.w};
    }

    float det = 1.0f;
    #pragma unroll
    for (int k = 0; k < NS; ++k) {
        float ukk = getel2(A2[k], k);
        det *= ukk;
        float pinv = __builtin_amdgcn_rcpf(ukk);
        #pragma unroll
        for (int r = k + 1; r < NS; ++r) {
            float m = getel2(A2[r], k) * pinv;
            v2f m2 = bc2(m);
            #pragma unroll
            for (int p = (k + 1) >> 1; p < 4; ++p)
                A2[r][p] = pkfma(-m2, A2[k][p], A2[r][p]);
            setel2(A2[r], k, m);
        }
        setel2(A2[k], k, pinv);
    }

    float tr = 0.0f;
    #pragma unroll
    for (int t = 0; t < 4; ++t) {
        const int k0 = 2 * t, k1 = 2 * t + 1;

        half8 hd0 = *(const half8*)(D2T + cols[k0] * TSTRH + eoff);
        half8 hd1 = *(const half8*)(D2T + cols[k1] * TSTRH + eoff);

        v2f y2[NS];
        y2[k0] = (v2f){1.0f, 0.0f};
        y2[k1] = (v2f){-getel2(A2[k1], k0), 1.0f};
        #pragma unroll
        for (int i = k1 + 1; i < NS; ++i) {
            v2f acc = (v2f){0.0f, 0.0f};
            #pragma unroll
            for (int j = k0; j < i; ++j)
                acc = pkfma(bc2(getel2(A2[i], j)), y2[j], acc);
            y2[i] = -acc;
        }

        v2f x2[NS];
        #pragma unroll
        for (int i = NS - 1; i >= 0; --i) {
            v2f acc = (i >= k0) ? y2[i] : (v2f){0.0f, 0.0f};
            #pragma unroll
            for (int c2 = i + 1; c2 < NS; ++c2)
                acc = pkfma(-bc2(getel2(A2[i], c2)), x2[c2], acc);
            x2[i] = acc * bc2(getel2(A2[i], i));
        }

        #pragma unroll
        for (int i = 0; i < NS; ++i) {
            tr = fmaf(x2[i].x, (float)hd0[i], tr);
            tr = fmaf(x2[i].y, (float)hd1[i], tr);
        }
    }

    det_out = det;
    tr_out  = tr;
}

// R13: two solves per thread from TWO DIFFERENT BATCHES, same (config,spin):
// same cols/eoff, different LDS buffers. Rationale: R2->R12 deltas (+6.1,
// +1.1, +0.8, +0.4 us) show a ~27 us invariant core = non-overlapped
// DS-phase + dependent-VALU-phase per wave at low waves/SIMD. Two inlined
// independent solves give the scheduler 32 A-b128s to issue back-to-back
// (DS busy under LU #1) and two independent LU chains (2x chain ILP).
// Also: 4 batches per barrier, grid halves to 2048 blocks.
// (OccupancyPercent is broken on gfx950 — fills read 8.5% while saturating —
// so R9/R10's residency theory was built on a bad counter; disregarded.)
__global__ __launch_bounds__(256)
void kp_x2_kernel(const float* __restrict__ MO,
                  const float* __restrict__ d2MO,
                  const int*   __restrict__ cfg_up,
                  const int*   __restrict__ cfg_dn,
                  float*       __restrict__ out)
{
    __shared__ float    smA[4][TSZ];         // [batch-slot][MO^T fp32, 32 x 20]
    __shared__ _Float16 smD[4][TSZH];        // [batch-slot][d2MO^T fp16, 32 x 24]

    const int tid = threadIdx.x;

    // ---- staging: thread-group q (64 threads) stages batch blockIdx*4+q ----
    {
        const int q = tid >> 6;              // batch slot 0..3
        const int w = tid & 63;
        const int b = blockIdx.x * 4 + q;
        const float* MOb = MO   + (size_t)b * NELEC * NMO;
        const float* d2b = d2MO + (size_t)b * NELEC * NMO;
        float*    MOT = smA[q];
        _Float16* D2T = smD[q];
        const int c = (w & 7) * 4;
        #pragma unroll
        for (int rr = 0; rr < 2; ++rr) {
            const int r = (w >> 3) + rr * 8; // rows 0..7 then 8..15
            float4 v = *(const float4*)(MOb + r * NMO + c);
            float4 d = *(const float4*)(d2b + r * NMO + c);
            MOT[(c + 0) * TSTR + r] = v.x;
            MOT[(c + 1) * TSTR + r] = v.y;
            MOT[(c + 2) * TSTR + r] = v.z;
            MOT[(c + 3) * TSTR + r] = v.w;
            D2T[(c + 0) * TSTRH + r] = (_Float16)d.x;
            D2T[(c + 1) * TSTRH + r] = (_Float16)d.y;
            D2T[(c + 2) * TSTRH + r] = (_Float16)d.z;
            D2T[(c + 3) * TSTRH + r] = (_Float16)d.w;
        }
    }
    __syncthreads();

    // ---- compute: s = bit0 (spin, partner = lane^1 in-wave), cc = bits1..6
    // (config), p = bit7 (batch pair): solves batch slots 2p and 2p+1 ----
    const int s  = tid & 1;
    const int cc = (tid >> 1) & 63;
    const int p  = tid >> 7;
    const int qa = 2 * p, qb = 2 * p + 1;
    const int eoff = s * NS;

    const int* cfg = s ? cfg_dn : cfg_up;
    int4 c0 = ((const int4*)cfg)[cc * 2 + 0];
    int4 c1 = ((const int4*)cfg)[cc * 2 + 1];
    const int cols[NS] = {c0.x, c0.y, c0.z, c0.w, c1.x, c1.y, c1.z, c1.w};

    float detA, trA, detB, trB;
    solve8T(smA[qa], smD[qa], cols, eoff, detA, trA);   // both inline into one
    solve8T(smA[qb], smD[qb], cols, eoff, detB, trB);   // block: scheduler
                                                        // interleaves the DAGs
    float detA_o = __shfl_xor(detA, 1);
    float trA_o  = __shfl_xor(trA, 1);
    float detB_o = __shfl_xor(detB, 1);
    float trB_o  = __shfl_xor(trB, 1);
    if (s == 0) {
        const size_t ba = (size_t)(blockIdx.x * 4 + qa) * NCONF + cc;
        const size_t bb = (size_t)(blockIdx.x * 4 + qb) * NCONF + cc;
        out[ba] = -0.5f * (trA + trA_o) * detA * detA_o;
        out[bb] = -0.5f * (trB + trB_o) * detB * detB_o;
    }
}

extern "C" void kernel_launch(void* const* d_in, const int* in_sizes, int n_in,
                              void* d_out, int out_size, void* d_ws, size_t ws_size,
                              hipStream_t stream)
{
    const float* MO     = (const float*)d_in[0];
    const float* d2MO   = (const float*)d_in[1];
    const int*   cfg_up = (const int*)d_in[2];
    const int*   cfg_dn = (const int*)d_in[3];
    float* out = (float*)d_out;

    dim3 grid(NBATCH / 4);   // 2048 blocks, 4 batches per block, 2 solves/thread
    dim3 block(256);
    kp_x2_kernel<<<grid, block, 0, stream>>>(MO, d2MO, cfg_up, cfg_dn, out);
}